// Round 17
// baseline (1325.345 us; speedup 1.0000x reference)
//
#include <hip/hip_runtime.h>

typedef __attribute__((ext_vector_type(4))) float f32x4;
typedef __attribute__((ext_vector_type(8))) short short8;

#define B_ 4
#define N_ 8192
#define E_ 131072
#define R_ 16
#define H_ 128
#define OUT_ 32
#define NKEYS (B_*N_*R_)   /* 524288 */
#define NEDGE (B_*E_)      /* 524288 */
#define NEXT_MASK 0x7FFFFu /* 19 bits: edge index 0..524287 */
#define NSEG 64
#define SEGCAP (NKEYS/NSEG) /* 8192 */

__device__ __forceinline__ unsigned short f2bf(float f){
  unsigned int u = __float_as_uint(f);
  u = (u + 0x7fffu + ((u>>16)&1u)) >> 16;
  return (unsigned short)u;
}
__device__ __forceinline__ float bfh(unsigned u, int hi){
  return __uint_as_float(hi ? (u & 0xffff0000u) : (u << 16));
}
__device__ __forceinline__ unsigned cvtpk(float lo, float hi){
  unsigned r;
  asm("v_cvt_pk_bf16_f32 %0, %1, %2" : "=v"(r) : "v"(lo), "v"(hi));
  return r;
}
__device__ __forceinline__ void glds16(const void* g, void* l){
  __builtin_amdgcn_global_load_lds((const __attribute__((address_space(1))) unsigned int*)g,
                                   (__attribute__((address_space(3))) unsigned int*)l,
                                   16, 0, 0);
}

// ---------------- edge chains: head[key] -> linked list over edges --------
// key = (((b<<13)+dst)<<4) + rel.  link[e] = (src<<19) | next_edge;
// next == self  means end-of-chain.

__global__ void link_k(const int* __restrict__ et, const int* __restrict__ ec,
                       int* __restrict__ head, unsigned* __restrict__ link){
  int e = blockIdx.x*256 + threadIdx.x;
  int b = e >> 17;                  // E = 2^17
  int2 sd = *(const int2*)(et + 2*e);
  int r  = ec[e];
  int key = (((b<<13)+sd.y)<<4) + r;
  int old = atomicExch(&head[key], e);
  unsigned nxt = (old < 0) ? (unsigned)e : (unsigned)old;
  link[e] = (((unsigned)sd.x) << 19) | nxt;
}

// ---------------- cmap + segmented worklist -------------------------------
// empty -> aggc slot 0 (zero block); single edge with mask==1 -> the h row
// itself (zero-copy); otherwise direct-mapped aggc slot 1+key AND appended
// to worklist segment key>>13 (r17: 64 counters — r16's single counter
// serialized 8192 wave-atomics, 99us; 64-way split runs them in parallel).

__global__ void cmap_k(const int* __restrict__ head, const unsigned* __restrict__ link,
                       const float* __restrict__ me,
                       int* __restrict__ cmapA, int* __restrict__ cmapB,
                       uint2* __restrict__ wlist, int* __restrict__ wcount,
                       int hARow, int hBRow, int aggcRow){
  int key = blockIdx.x*256 + threadIdx.x;
  int hd = head[key];
  int vA = aggcRow, vB = aggcRow;          // zero slot
  if (hd >= 0) {
    unsigned lk = link[hd];
    int nxt = (int)(lk & NEXT_MASK);
    if (nxt == hd && me[hd] == 1.0f) {
      int noderow = ((key >> 17) << 13) + (int)(lk >> 19);
      vA = hARow + noderow;
      vB = hBRow + noderow;
    } else {
      vA = aggcRow + 1 + key;
      vB = vA;
      int seg = key >> 13;                 // 64 segments of 8192 keys
      int pos = atomicAdd(&wcount[seg], 1);
      wlist[(seg << 13) + pos] = make_uint2((unsigned)key, (unsigned)hd);
    }
  }
  cmapA[key] = vA;
  cmapB[key] = vB;
}

// ---------------- feature prep (embed + 3x W-transpose + zero slot) -------

__global__ void prep_k(const int* __restrict__ cls, const float* __restrict__ emb,
                       const float* __restrict__ W1, const float* __restrict__ W2,
                       const float* __restrict__ W3,
                       unsigned short* __restrict__ h,
                       unsigned short* __restrict__ W1t,
                       unsigned short* __restrict__ W2t,
                       unsigned short* __restrict__ W3t,
                       unsigned short* __restrict__ aggc){
  int t = blockIdx.x*256 + threadIdx.x;
  if (blockIdx.x == 0 && threadIdx.x < 16) {
    *(uint4*)((char*)aggc + threadIdx.x*16) = make_uint4(0,0,0,0);  // zero slot
  }
  if (t < B_*N_*32) {
    int node = t>>5, c = t&31;
    int cl = cls[node];
    float4 v = *(const float4*)(emb + cl*H_ + c*4);
    uint2 o;
    o.x = f2bf(v.x) | ((unsigned int)f2bf(v.y)<<16);
    o.y = f2bf(v.z) | ((unsigned int)f2bf(v.w)<<16);
    *(uint2*)(h + node*H_ + c*4) = o;
  } else {
    int u = t - B_*N_*32;
    if (u < R_*H_*H_) {
      int k = u & 127, n = (u>>7) & 127, r = u >> 14;
      W1t[u] = f2bf(W1[(r*H_ + k)*H_ + n]);
    } else if (u < 2*R_*H_*H_) {
      int u2 = u - R_*H_*H_;
      int k = u2 & 127, n = (u2>>7) & 127, r = u2 >> 14;
      W2t[u2] = f2bf(W2[(r*H_ + k)*H_ + n]);
    } else {
      int u2 = u - 2*R_*H_*H_;
      if (u2 < R_*OUT_*H_) {
        int k = u2 & 127, n = (u2>>7) & 31, r = u2 >> 12;
        W3t[u2] = f2bf(W3[(r*H_ + k)*OUT_ + n]);
      }
    }
  }
}

// ---------------- aggregation over segmented worklist ---------------------
// Block blk serves segment blk>>7; entry idx = (blk&127)*64 + tid/4.
// Lanes dense within a segment; blocks past wcount[seg] exit on one load.

__global__ __launch_bounds__(256) void agg_k(
    const unsigned short* __restrict__ h_in,   // bf16 [B*N*H]
    const uint2* __restrict__ wlist,           // 64 segments x 8192 {key, head}
    const int* __restrict__ wcount,            // [64]
    const unsigned* __restrict__ link,
    const float* __restrict__ me,
    unsigned short* __restrict__ aggc){        // bf16 [1+NKEYS][128]
  const int seg = blockIdx.x >> 7;             // 128 blocks per segment
  const int idx = ((blockIdx.x & 127) << 6) + (threadIdx.x >> 2);
  if (idx >= wcount[seg]) return;
  const int q = threadIdx.x & 3;
  uint2 wk = wlist[(seg << 13) + idx];
  const int key = (int)wk.x;
  const int hd  = (int)wk.y;
  const int b   = key >> 17;
  const unsigned short* hb = h_in + ((size_t)b << 20);

  float fa[32];
  #pragma unroll
  for (int i=0;i<32;++i) fa[i] = 0.f;

#define UNP8(FP, V, M) do { \
  (FP)[0]+=M*bfh((V).x,0); (FP)[1]+=M*bfh((V).x,1); \
  (FP)[2]+=M*bfh((V).y,0); (FP)[3]+=M*bfh((V).y,1); \
  (FP)[4]+=M*bfh((V).z,0); (FP)[5]+=M*bfh((V).z,1); \
  (FP)[6]+=M*bfh((V).w,0); (FP)[7]+=M*bfh((V).w,1); \
} while(0)
#define MAC32(SRC, M) do { \
  const uint4* hp_ = (const uint4*)(hb + (((unsigned)(SRC))<<7) + (q<<5)); \
  uint4 v0_ = hp_[0], v1_ = hp_[1], v2_ = hp_[2], v3_ = hp_[3]; \
  UNP8(fa+0,  v0_, M); UNP8(fa+8,  v1_, M); \
  UNP8(fa+16, v2_, M); UNP8(fa+24, v3_, M); \
} while(0)

  int cur = hd;
  unsigned clk = link[cur];
  float cm = me[cur];
  for (;;) {
    int src = (int)(clk >> 19);
    MAC32(src, cm);
    int nx = (int)(clk & NEXT_MASK);
    if (nx == cur) break;
    cur = nx;
    clk = link[cur];
    cm  = me[cur];
  }
#undef MAC32
#undef UNP8

  unsigned short* ap = aggc + (((size_t)(1 + key)) << 7) + (q<<5);
  #pragma unroll
  for (int c = 0; c < 4; ++c) {
    uint4 pk;
    pk.x = cvtpk(fa[c*8+0], fa[c*8+1]);
    pk.y = cvtpk(fa[c*8+2], fa[c*8+3]);
    pk.z = cvtpk(fa[c*8+4], fa[c*8+5]);
    pk.w = cvtpk(fa[c*8+6], fa[c*8+7]);
    *(uint4*)(ap + c*8) = pk;
  }
}

// ---------------- dense GEMM over virtual-row A (LDS, 3-deep pipeline) ----
// A rows live anywhere in ws (aggc slots OR h rows, all 256B-aligned):
// cmap[key] is the virtual row index from ws base. NOUT=128: MT=128, 1024
// thr, grid 256. NOUT=32: MT=64, 512 thr, grid 512, fused softmax;
// A-staging is ONE 16B unit per thread (r14 fix, kept).
// Counted vmcnt (never 0 in main loop); pre-swizzled glds source (rule 21).

template<int NOUT>
__global__ __launch_bounds__((NOUT==128) ? 1024 : 512, 4) void gemm_k(
    const unsigned short* __restrict__ base,   // ws base (row 0)
    const int* __restrict__ cmap,              // [NKEYS] virtual rows
    const unsigned short* __restrict__ Wt,     // bf16 [R][NOUT][H]
    const float* __restrict__ mobj,            // [B*N] (NOUT=32)
    unsigned short* __restrict__ h_out,        // bf16 (NOUT=128)
    float* __restrict__ out)                   // fp32 (NOUT=32)
{
  constexpr int MT  = (NOUT==128) ? 128 : 64;
  constexpr int MI  = (NOUT==128) ? 2 : 1;
  constexpr int NIw = (NOUT==128) ? 2 : 1;
  __shared__ __align__(16) unsigned short A_s[3][MT*64];    // 48 / 24 KB
  __shared__ __align__(16) unsigned short B_s[3][NOUT*64];  // 48 / 12 KB
  __shared__ int cmap_s[MT*16];                             // 8 / 4 KB
  __shared__ float comb[(NOUT==32) ? 64*33 : 1];            // 8.4 KB (NOUT=32)

  const int tid  = threadIdx.x;
  const int lane = tid & 63;
  const int w    = tid >> 6;
  const int c16  = lane & 15;
  const int g    = lane >> 4;
  const int m0   = blockIdx.x * MT;
  const int mbase = (NOUT==128) ? ((w>>2)<<5) : ((w>>1)<<4);
  const int nbase = (NOUT==128) ? ((w&3)<<5) : ((w&1)<<4);

  *(int2*)&cmap_s[tid<<1] = *(const int2*)(cmap + m0*16 + (tid<<1));
  __syncthreads();

#define STAGE(KC, BUF) do { \
  const int kc_ = (KC); \
  { \
    int m_ = tid>>3, u_ = tid&7; \
    int cm_ = cmap_s[(m_<<4) + (kc_>>1)]; \
    glds16((const char*)base + ((size_t)cm_<<8) + ((kc_&1)<<7) + ((u_ ^ (m_&7))<<4), \
           &A_s[BUF][tid<<3]); \
  } \
  if constexpr (NOUT==128) { \
    int n_ = tid>>3, u_ = tid&7; \
    glds16((const char*)Wt + ((size_t)((kc_>>1)*128 + n_)<<8) + ((kc_&1)<<7) + ((u_ ^ (n_&7))<<4), \
           &B_s[BUF][tid<<3]); \
  } else { \
    if (w < 4) { \
      int uid_ = (w<<6) + lane; \
      int n_ = uid_>>3, u_ = uid_&7; \
      glds16((const char*)Wt + ((size_t)((kc_>>1)*32 + n_)<<8) + ((kc_&1)<<7) + ((u_ ^ (n_&7))<<4), \
             &B_s[BUF][uid_<<3]); } \
  } \
} while(0)

// per-wave loads/stage: NOUT=128 -> 2 (A+B); NOUT=32 -> w<4: 2, w>=4: 1.
#define WAIT_MAIN do { \
  if constexpr (NOUT==128) { asm volatile("s_waitcnt vmcnt(4)" ::: "memory"); } \
  else { if (w < 4) asm volatile("s_waitcnt vmcnt(4)" ::: "memory"); \
         else       asm volatile("s_waitcnt vmcnt(2)" ::: "memory"); } \
} while(0)
#define WAIT_T1 do { \
  if constexpr (NOUT==128) { asm volatile("s_waitcnt vmcnt(2)" ::: "memory"); } \
  else { if (w < 4) asm volatile("s_waitcnt vmcnt(2)" ::: "memory"); \
         else       asm volatile("s_waitcnt vmcnt(1)" ::: "memory"); } \
} while(0)

  f32x4 acc[MI][NIw];
  #pragma unroll
  for (int mi=0; mi<MI; ++mi)
    #pragma unroll
    for (int ni=0; ni<NIw; ++ni)
      acc[mi][ni] = f32x4{0.f,0.f,0.f,0.f};

#define COMPUTE(BUF) do { \
  _Pragma("unroll") \
  for (int kk=0; kk<2; ++kk) { \
    short8 af[MI], bfr[NIw]; \
    _Pragma("unroll") \
    for (int mi=0; mi<MI; ++mi) { \
      int m_ = mbase + mi*16 + c16; \
      af[mi] = *(const short8*)((const char*)&A_s[BUF][0] + m_*128 \
               + (((kk<<6) + (g<<4)) ^ ((m_&7)<<4))); } \
    _Pragma("unroll") \
    for (int ni=0; ni<NIw; ++ni) { \
      int n_ = nbase + ni*16 + c16; \
      bfr[ni] = *(const short8*)((const char*)&B_s[BUF][0] + n_*128 \
               + (((kk<<6) + (g<<4)) ^ ((n_&7)<<4))); } \
    _Pragma("unroll") \
    for (int mi=0; mi<MI; ++mi) \
      _Pragma("unroll") \
      for (int ni=0; ni<NIw; ++ni) \
        acc[mi][ni] = __builtin_amdgcn_mfma_f32_16x16x32_bf16(af[mi], bfr[ni], acc[mi][ni], 0,0,0); \
  } \
} while(0)

  STAGE(0, 0);
  STAGE(1, 1);
  for (int kc = 0; kc < 30; ++kc) {
    STAGE(kc+2, (kc+2)%3);
    WAIT_MAIN;
    __builtin_amdgcn_s_barrier();
    COMPUTE(kc%3);
    asm volatile("s_waitcnt lgkmcnt(0)" ::: "memory");
    __builtin_amdgcn_s_barrier();
  }
  // kc = 30
  WAIT_T1;
  __builtin_amdgcn_s_barrier();
  COMPUTE(0);
  asm volatile("s_waitcnt lgkmcnt(0)" ::: "memory");
  __builtin_amdgcn_s_barrier();
  // kc = 31
  asm volatile("s_waitcnt vmcnt(0)" ::: "memory");
  __builtin_amdgcn_s_barrier();
  COMPUTE(1);

  if constexpr (NOUT == 128) {
    #pragma unroll
    for (int mi=0; mi<MI; ++mi)
      #pragma unroll
      for (int ni=0; ni<NIw; ++ni)
        #pragma unroll
        for (int j=0; j<4; ++j) {
          int row = mbase + mi*16 + (g<<2) + j;
          int col = nbase + ni*16 + c16;
          h_out[((size_t)(m0+row)<<7) + col] = f2bf(fmaxf(acc[mi][ni][j], 0.f));
        }
  } else {
    #pragma unroll
    for (int j=0; j<4; ++j)
      comb[(mbase + (g<<2) + j)*33 + nbase + c16] = acc[0][0][j];
    __syncthreads();
    if (tid < 64) {
      const int row = tid;
      float v[32];
      #pragma unroll
      for (int c=0; c<32; ++c) v[c] = comb[row*33 + c];
      float mx = v[0];
      #pragma unroll
      for (int c=1; c<32; ++c) mx = fmaxf(mx, v[c]);
      float sm = 0.f;
      #pragma unroll
      for (int c=0; c<32; ++c){ v[c] = __expf(v[c]-mx); sm += v[c]; }
      float sc = mobj[m0+row] / sm;
      float4* op = (float4*)(out + ((size_t)(m0+row)<<5));
      #pragma unroll
      for (int c=0; c<8; ++c)
        op[c] = make_float4(v[4*c]*sc, v[4*c+1]*sc, v[4*c+2]*sc, v[4*c+3]*sc);
    }
  }
#undef STAGE
#undef WAIT_MAIN
#undef WAIT_T1
#undef COMPUTE
}

extern "C" void kernel_launch(void* const* d_in, const int* in_sizes, int n_in,
                              void* d_out, int out_size, void* d_ws, size_t ws_size,
                              hipStream_t stream){
  const int*   cls   = (const int*)  d_in[0];
  // d_in[1] states_objects: unused by reference
  const int*   et    = (const int*)  d_in[2];
  const int*   ec    = (const int*)  d_in[3];
  const float* mobj  = (const float*)d_in[4];
  const float* medge = (const float*)d_in[5];
  const float* emb   = (const float*)d_in[6];
  const float* W1    = (const float*)d_in[7];
  const float* W2    = (const float*)d_in[8];
  const float* W3    = (const float*)d_in[9];
  float* out = (float*)d_out;

  char* ws = (char*)d_ws;
  size_t o = 0;
  auto alloc = [&](size_t bytes)->char*{
    char* p = ws + o;
    o += (bytes + 255) & ~(size_t)255;
    return p;
  };
  unsigned short* hA    = (unsigned short*)alloc((size_t)B_*N_*H_*2);   // 8 MB
  unsigned short* hB    = (unsigned short*)alloc((size_t)B_*N_*H_*2);   // 8 MB
  unsigned short* W1t   = (unsigned short*)alloc((size_t)R_*H_*H_*2);   // 4 MB
  unsigned short* W2t   = (unsigned short*)alloc((size_t)R_*H_*H_*2);   // 4 MB
  unsigned short* W3t   = (unsigned short*)alloc((size_t)R_*OUT_*H_*2); // 1 MB
  int*            head  = (int*)alloc((size_t)NKEYS*4);                 // 2 MB
  unsigned*       link  = (unsigned*)alloc((size_t)NEDGE*4);            // 2 MB
  int*            cmapA = (int*)alloc((size_t)NKEYS*4);                 // 2 MB
  int*            cmapB = (int*)alloc((size_t)NKEYS*4);                 // 2 MB
  uint2*          wlist = (uint2*)alloc((size_t)NKEYS*8);               // 4 MB
  int*            wcount= (int*)alloc(NSEG*4);
  unsigned short* aggc  = (unsigned short*)alloc(((size_t)NKEYS+1)*H_*2); // 128 MB
  (void)ws_size; (void)in_sizes; (void)n_in; (void)out_size;

  const int hARow   = (int)(((char*)hA   - ws) >> 8);   // 0
  const int hBRow   = (int)(((char*)hB   - ws) >> 8);
  const int aggcRow = (int)(((char*)aggc - ws) >> 8);
  const unsigned short* vbase = (const unsigned short*)ws;

  // edge chains + segmented worklist + virtual-row maps
  hipMemsetAsync(head, 0xFF, (size_t)NKEYS*4, stream);
  hipMemsetAsync(wcount, 0, NSEG*4, stream);
  hipLaunchKernelGGL(link_k, dim3(NEDGE/256), dim3(256), 0, stream, et, ec, head, link);
  hipLaunchKernelGGL(cmap_k, dim3(NKEYS/256), dim3(256), 0, stream, head, link, medge,
                     cmapA, cmapB, wlist, wcount, hARow, hBRow, aggcRow);

  // h0 = bf16(embed[class]);  W -> bf16 [r][n][k];  zero slot 0 of aggc
  hipLaunchKernelGGL(prep_k, dim3((B_*N_*32 + 2*R_*H_*H_ + R_*OUT_*H_)/256), dim3(256), 0, stream,
                     cls, emb, W1, W2, W3, hA, W1t, W2t, W3t, aggc);

  const int aggGrid = NSEG*128;        // 8192 (worst case; excess blocks exit)
  const int g128    = (B_*N_)/128;     // 256 blocks x 1024 thr
  const int g32     = (B_*N_)/64;      // 512 blocks x 512 thr

  // layer 1 (h = hA, zero-copy rows via cmapA)
  hipLaunchKernelGGL(agg_k, dim3(aggGrid), dim3(256), 0, stream, hA, wlist, wcount, link, medge, aggc);
  hipLaunchKernelGGL((gemm_k<128>), dim3(g128), dim3(1024), 0, stream,
                     vbase, cmapA, W1t, (const float*)nullptr, hB, (float*)nullptr);
  // layer 2 (h = hB)
  hipLaunchKernelGGL(agg_k, dim3(aggGrid), dim3(256), 0, stream, hB, wlist, wcount, link, medge, aggc);
  hipLaunchKernelGGL((gemm_k<128>), dim3(g128), dim3(1024), 0, stream,
                     vbase, cmapB, W2t, (const float*)nullptr, hA, (float*)nullptr);
  // layer 3 (h = hA, + fused softmax * mask)
  hipLaunchKernelGGL(agg_k, dim3(aggGrid), dim3(256), 0, stream, hA, wlist, wcount, link, medge, aggc);
  hipLaunchKernelGGL((gemm_k<32>), dim3(g32), dim3(512), 0, stream,
                     vbase, cmapA, W3t, mobj, (unsigned short*)nullptr, out);
}

// Round 18
// 207.136 us; speedup vs baseline: 6.3984x; 6.3984x over previous
//
#include <hip/hip_runtime.h>

typedef __attribute__((ext_vector_type(4))) float f32x4;
typedef __attribute__((ext_vector_type(8))) short short8;

#define B_ 4
#define N_ 8192
#define E_ 131072
#define R_ 16
#define H_ 128
#define OUT_ 32
#define NKEYS (B_*N_*R_)   /* 524288 */
#define NEDGE (B_*E_)      /* 524288 */
#define NEXT_MASK 0x7FFFFu /* 19 bits: edge index 0..524287 */

__device__ __forceinline__ unsigned short f2bf(float f){
  unsigned int u = __float_as_uint(f);
  u = (u + 0x7fffu + ((u>>16)&1u)) >> 16;
  return (unsigned short)u;
}
__device__ __forceinline__ float bfh(unsigned u, int hi){
  return __uint_as_float(hi ? (u & 0xffff0000u) : (u << 16));
}
__device__ __forceinline__ unsigned cvtpk(float lo, float hi){
  unsigned r;
  asm("v_cvt_pk_bf16_f32 %0, %1, %2" : "=v"(r) : "v"(lo), "v"(hi));
  return r;
}
__device__ __forceinline__ void glds16(const void* g, void* l){
  __builtin_amdgcn_global_load_lds((const __attribute__((address_space(1))) unsigned int*)g,
                                   (__attribute__((address_space(3))) unsigned int*)l,
                                   16, 0, 0);
}

// ---------------- edge chains: head[key] -> linked list over edges --------
// key = (((b<<13)+dst)<<4) + rel.  link[e] = (src<<19) | next_edge;
// next == self  means end-of-chain.

__global__ void link_k(const int* __restrict__ et, const int* __restrict__ ec,
                       int* __restrict__ head, unsigned* __restrict__ link){
  int e = blockIdx.x*256 + threadIdx.x;
  int b = e >> 17;                  // E = 2^17
  int2 sd = *(const int2*)(et + 2*e);
  int r  = ec[e];
  int key = (((b<<13)+sd.y)<<4) + r;
  int old = atomicExch(&head[key], e);
  unsigned nxt = (old < 0) ? (unsigned)e : (unsigned)old;
  link[e] = (((unsigned)sd.x) << 19) | nxt;
}

// ---------------- cmap: virtual A-row per (key, layer-input) --------------
// empty -> aggc slot 0 (the zero block, row aggcRow); single edge with
// mask==1 -> the h row itself (zero-copy); otherwise direct-mapped aggc
// slot 1+key.  (r16/r17 worklist experiments reverted: single-counter
// wave-atomics cost 99us, per-lane segmented atomics 1163us, and the
// compacted agg only saved ~5us total — not worth it.)

__global__ void cmap_k(const int* __restrict__ head, const unsigned* __restrict__ link,
                       const float* __restrict__ me,
                       int* __restrict__ cmapA, int* __restrict__ cmapB,
                       int hARow, int hBRow, int aggcRow){
  int key = blockIdx.x*256 + threadIdx.x;
  int hd = head[key];
  int vA = aggcRow, vB = aggcRow;          // zero slot
  if (hd >= 0) {
    unsigned lk = link[hd];
    int nxt = (int)(lk & NEXT_MASK);
    if (nxt == hd && me[hd] == 1.0f) {
      int noderow = ((key >> 17) << 13) + (int)(lk >> 19);
      vA = hARow + noderow;
      vB = hBRow + noderow;
    } else {
      vA = aggcRow + 1 + key;
      vB = vA;
    }
  }
  cmapA[key] = vA;
  cmapB[key] = vB;
}

// ---------------- feature prep (embed + 3x W-transpose + zero slot) -------

__global__ void prep_k(const int* __restrict__ cls, const float* __restrict__ emb,
                       const float* __restrict__ W1, const float* __restrict__ W2,
                       const float* __restrict__ W3,
                       unsigned short* __restrict__ h,
                       unsigned short* __restrict__ W1t,
                       unsigned short* __restrict__ W2t,
                       unsigned short* __restrict__ W3t,
                       unsigned short* __restrict__ aggc){
  int t = blockIdx.x*256 + threadIdx.x;
  if (blockIdx.x == 0 && threadIdx.x < 16) {
    *(uint4*)((char*)aggc + threadIdx.x*16) = make_uint4(0,0,0,0);  // zero slot
  }
  if (t < B_*N_*32) {
    int node = t>>5, c = t&31;
    int cl = cls[node];
    float4 v = *(const float4*)(emb + cl*H_ + c*4);
    uint2 o;
    o.x = f2bf(v.x) | ((unsigned int)f2bf(v.y)<<16);
    o.y = f2bf(v.z) | ((unsigned int)f2bf(v.w)<<16);
    *(uint2*)(h + node*H_ + c*4) = o;
  } else {
    int u = t - B_*N_*32;
    if (u < R_*H_*H_) {
      int k = u & 127, n = (u>>7) & 127, r = u >> 14;
      W1t[u] = f2bf(W1[(r*H_ + k)*H_ + n]);
    } else if (u < 2*R_*H_*H_) {
      int u2 = u - R_*H_*H_;
      int k = u2 & 127, n = (u2>>7) & 127, r = u2 >> 14;
      W2t[u2] = f2bf(W2[(r*H_ + k)*H_ + n]);
    } else {
      int u2 = u - 2*R_*H_*H_;
      if (u2 < R_*OUT_*H_) {
        int k = u2 & 127, n = (u2>>7) & 31, r = u2 >> 12;
        W3t[u2] = f2bf(W3[(r*H_ + k)*OUT_ + n]);
      }
    }
  }
}

// ---------------- aggregation (chain walk; skips zero-copy keys) ----------
// XCD x = blk&7 serves batch x>>1 only -> per-XCD h slice = 2MB < 4MB L2.

__global__ __launch_bounds__(256) void agg_k(
    const unsigned short* __restrict__ h_in,   // bf16 [B*N*H]
    const int* __restrict__ head,
    const unsigned* __restrict__ link,
    const float* __restrict__ me,
    unsigned short* __restrict__ aggc){        // bf16 [1+NKEYS][128]
  const int orig = blockIdx.x;                 // 8192
  const int x    = orig & 7;                   // XCD (round-robin dispatch)
  const int b    = x >> 1;
  const int lb   = ((x & 1) << 10) + (orig >> 3);   // 0..2047 within batch
  const int key  = (b << 17) + (lb << 6) + (threadIdx.x >> 2);
  const int q    = threadIdx.x & 3;
  int hd = head[key];
  if (hd < 0) return;
  unsigned lk = link[hd];
  int nxt = (int)(lk & NEXT_MASK);
  float m0 = me[hd];
  if (nxt == hd && m0 == 1.0f) return;         // zero-copy key: gemm reads h
  const unsigned short* hb = h_in + ((size_t)b << 20);

  float fa[32];
  #pragma unroll
  for (int i=0;i<32;++i) fa[i] = 0.f;

#define UNP8(FP, V, M) do { \
  (FP)[0]+=M*bfh((V).x,0); (FP)[1]+=M*bfh((V).x,1); \
  (FP)[2]+=M*bfh((V).y,0); (FP)[3]+=M*bfh((V).y,1); \
  (FP)[4]+=M*bfh((V).z,0); (FP)[5]+=M*bfh((V).z,1); \
  (FP)[6]+=M*bfh((V).w,0); (FP)[7]+=M*bfh((V).w,1); \
} while(0)
#define MAC32(SRC, M) do { \
  const uint4* hp_ = (const uint4*)(hb + (((unsigned)(SRC))<<7) + (q<<5)); \
  uint4 v0_ = hp_[0], v1_ = hp_[1], v2_ = hp_[2], v3_ = hp_[3]; \
  UNP8(fa+0,  v0_, M); UNP8(fa+8,  v1_, M); \
  UNP8(fa+16, v2_, M); UNP8(fa+24, v3_, M); \
} while(0)

  int cur = hd;
  unsigned clk = lk;
  float cm = m0;
  for (;;) {
    int src = (int)(clk >> 19);
    MAC32(src, cm);
    int nx = (int)(clk & NEXT_MASK);
    if (nx == cur) break;
    cur = nx;
    clk = link[cur];
    cm  = me[cur];
  }
#undef MAC32
#undef UNP8

  unsigned short* ap = aggc + (((size_t)(1 + key)) << 7) + (q<<5);
  #pragma unroll
  for (int c = 0; c < 4; ++c) {
    uint4 pk;
    pk.x = cvtpk(fa[c*8+0], fa[c*8+1]);
    pk.y = cvtpk(fa[c*8+2], fa[c*8+3]);
    pk.z = cvtpk(fa[c*8+4], fa[c*8+5]);
    pk.w = cvtpk(fa[c*8+6], fa[c*8+7]);
    *(uint4*)(ap + c*8) = pk;
  }
}

// ---------------- dense GEMM over virtual-row A (LDS, 3-deep pipeline) ----
// A rows live anywhere in ws (aggc slots OR h rows, all 256B-aligned):
// cmap[key] is the virtual row index from ws base. NOUT=128: MT=128, 1024
// thr, grid 256. NOUT=32: MT=64, 512 thr, grid 512, fused softmax;
// A-staging is ONE 16B unit per thread (r14 fix, kept).
// Counted vmcnt (never 0 in main loop); pre-swizzled glds source (rule 21).

template<int NOUT>
__global__ __launch_bounds__((NOUT==128) ? 1024 : 512, 4) void gemm_k(
    const unsigned short* __restrict__ base,   // ws base (row 0)
    const int* __restrict__ cmap,              // [NKEYS] virtual rows
    const unsigned short* __restrict__ Wt,     // bf16 [R][NOUT][H]
    const float* __restrict__ mobj,            // [B*N] (NOUT=32)
    unsigned short* __restrict__ h_out,        // bf16 (NOUT=128)
    float* __restrict__ out)                   // fp32 (NOUT=32)
{
  constexpr int MT  = (NOUT==128) ? 128 : 64;
  constexpr int MI  = (NOUT==128) ? 2 : 1;
  constexpr int NIw = (NOUT==128) ? 2 : 1;
  __shared__ __align__(16) unsigned short A_s[3][MT*64];    // 48 / 24 KB
  __shared__ __align__(16) unsigned short B_s[3][NOUT*64];  // 48 / 12 KB
  __shared__ int cmap_s[MT*16];                             // 8 / 4 KB
  __shared__ float comb[(NOUT==32) ? 64*33 : 1];            // 8.4 KB (NOUT=32)

  const int tid  = threadIdx.x;
  const int lane = tid & 63;
  const int w    = tid >> 6;
  const int c16  = lane & 15;
  const int g    = lane >> 4;
  const int m0   = blockIdx.x * MT;
  const int mbase = (NOUT==128) ? ((w>>2)<<5) : ((w>>1)<<4);
  const int nbase = (NOUT==128) ? ((w&3)<<5) : ((w&1)<<4);

  *(int2*)&cmap_s[tid<<1] = *(const int2*)(cmap + m0*16 + (tid<<1));
  __syncthreads();

#define STAGE(KC, BUF) do { \
  const int kc_ = (KC); \
  { \
    int m_ = tid>>3, u_ = tid&7; \
    int cm_ = cmap_s[(m_<<4) + (kc_>>1)]; \
    glds16((const char*)base + ((size_t)cm_<<8) + ((kc_&1)<<7) + ((u_ ^ (m_&7))<<4), \
           &A_s[BUF][tid<<3]); \
  } \
  if constexpr (NOUT==128) { \
    int n_ = tid>>3, u_ = tid&7; \
    glds16((const char*)Wt + ((size_t)((kc_>>1)*128 + n_)<<8) + ((kc_&1)<<7) + ((u_ ^ (n_&7))<<4), \
           &B_s[BUF][tid<<3]); \
  } else { \
    if (w < 4) { \
      int uid_ = (w<<6) + lane; \
      int n_ = uid_>>3, u_ = uid_&7; \
      glds16((const char*)Wt + ((size_t)((kc_>>1)*32 + n_)<<8) + ((kc_&1)<<7) + ((u_ ^ (n_&7))<<4), \
             &B_s[BUF][uid_<<3]); } \
  } \
} while(0)

// per-wave loads/stage: NOUT=128 -> 2 (A+B); NOUT=32 -> w<4: 2, w>=4: 1.
#define WAIT_MAIN do { \
  if constexpr (NOUT==128) { asm volatile("s_waitcnt vmcnt(4)" ::: "memory"); } \
  else { if (w < 4) asm volatile("s_waitcnt vmcnt(4)" ::: "memory"); \
         else       asm volatile("s_waitcnt vmcnt(2)" ::: "memory"); } \
} while(0)
#define WAIT_T1 do { \
  if constexpr (NOUT==128) { asm volatile("s_waitcnt vmcnt(2)" ::: "memory"); } \
  else { if (w < 4) asm volatile("s_waitcnt vmcnt(2)" ::: "memory"); \
         else       asm volatile("s_waitcnt vmcnt(1)" ::: "memory"); } \
} while(0)

  f32x4 acc[MI][NIw];
  #pragma unroll
  for (int mi=0; mi<MI; ++mi)
    #pragma unroll
    for (int ni=0; ni<NIw; ++ni)
      acc[mi][ni] = f32x4{0.f,0.f,0.f,0.f};

#define COMPUTE(BUF) do { \
  _Pragma("unroll") \
  for (int kk=0; kk<2; ++kk) { \
    short8 af[MI], bfr[NIw]; \
    _Pragma("unroll") \
    for (int mi=0; mi<MI; ++mi) { \
      int m_ = mbase + mi*16 + c16; \
      af[mi] = *(const short8*)((const char*)&A_s[BUF][0] + m_*128 \
               + (((kk<<6) + (g<<4)) ^ ((m_&7)<<4))); } \
    _Pragma("unroll") \
    for (int ni=0; ni<NIw; ++ni) { \
      int n_ = nbase + ni*16 + c16; \
      bfr[ni] = *(const short8*)((const char*)&B_s[BUF][0] + n_*128 \
               + (((kk<<6) + (g<<4)) ^ ((n_&7)<<4))); } \
    _Pragma("unroll") \
    for (int mi=0; mi<MI; ++mi) \
      _Pragma("unroll") \
      for (int ni=0; ni<NIw; ++ni) \
        acc[mi][ni] = __builtin_amdgcn_mfma_f32_16x16x32_bf16(af[mi], bfr[ni], acc[mi][ni], 0,0,0); \
  } \
} while(0)

  STAGE(0, 0);
  STAGE(1, 1);
  for (int kc = 0; kc < 30; ++kc) {
    STAGE(kc+2, (kc+2)%3);
    WAIT_MAIN;
    __builtin_amdgcn_s_barrier();
    COMPUTE(kc%3);
    asm volatile("s_waitcnt lgkmcnt(0)" ::: "memory");
    __builtin_amdgcn_s_barrier();
  }
  // kc = 30
  WAIT_T1;
  __builtin_amdgcn_s_barrier();
  COMPUTE(0);
  asm volatile("s_waitcnt lgkmcnt(0)" ::: "memory");
  __builtin_amdgcn_s_barrier();
  // kc = 31
  asm volatile("s_waitcnt vmcnt(0)" ::: "memory");
  __builtin_amdgcn_s_barrier();
  COMPUTE(1);

  if constexpr (NOUT == 128) {
    #pragma unroll
    for (int mi=0; mi<MI; ++mi)
      #pragma unroll
      for (int ni=0; ni<NIw; ++ni)
        #pragma unroll
        for (int j=0; j<4; ++j) {
          int row = mbase + mi*16 + (g<<2) + j;
          int col = nbase + ni*16 + c16;
          h_out[((size_t)(m0+row)<<7) + col] = f2bf(fmaxf(acc[mi][ni][j], 0.f));
        }
  } else {
    #pragma unroll
    for (int j=0; j<4; ++j)
      comb[(mbase + (g<<2) + j)*33 + nbase + c16] = acc[0][0][j];
    __syncthreads();
    if (tid < 64) {
      const int row = tid;
      float v[32];
      #pragma unroll
      for (int c=0; c<32; ++c) v[c] = comb[row*33 + c];
      float mx = v[0];
      #pragma unroll
      for (int c=1; c<32; ++c) mx = fmaxf(mx, v[c]);
      float sm = 0.f;
      #pragma unroll
      for (int c=0; c<32; ++c){ v[c] = __expf(v[c]-mx); sm += v[c]; }
      float sc = mobj[m0+row] / sm;
      float4* op = (float4*)(out + ((size_t)(m0+row)<<5));
      #pragma unroll
      for (int c=0; c<8; ++c)
        op[c] = make_float4(v[4*c]*sc, v[4*c+1]*sc, v[4*c+2]*sc, v[4*c+3]*sc);
    }
  }
#undef STAGE
#undef WAIT_MAIN
#undef WAIT_T1
#undef COMPUTE
}

extern "C" void kernel_launch(void* const* d_in, const int* in_sizes, int n_in,
                              void* d_out, int out_size, void* d_ws, size_t ws_size,
                              hipStream_t stream){
  const int*   cls   = (const int*)  d_in[0];
  // d_in[1] states_objects: unused by reference
  const int*   et    = (const int*)  d_in[2];
  const int*   ec    = (const int*)  d_in[3];
  const float* mobj  = (const float*)d_in[4];
  const float* medge = (const float*)d_in[5];
  const float* emb   = (const float*)d_in[6];
  const float* W1    = (const float*)d_in[7];
  const float* W2    = (const float*)d_in[8];
  const float* W3    = (const float*)d_in[9];
  float* out = (float*)d_out;

  char* ws = (char*)d_ws;
  size_t o = 0;
  auto alloc = [&](size_t bytes)->char*{
    char* p = ws + o;
    o += (bytes + 255) & ~(size_t)255;
    return p;
  };
  unsigned short* hA    = (unsigned short*)alloc((size_t)B_*N_*H_*2);   // 8 MB
  unsigned short* hB    = (unsigned short*)alloc((size_t)B_*N_*H_*2);   // 8 MB
  unsigned short* W1t   = (unsigned short*)alloc((size_t)R_*H_*H_*2);   // 4 MB
  unsigned short* W2t   = (unsigned short*)alloc((size_t)R_*H_*H_*2);   // 4 MB
  unsigned short* W3t   = (unsigned short*)alloc((size_t)R_*OUT_*H_*2); // 1 MB
  int*            head  = (int*)alloc((size_t)NKEYS*4);                 // 2 MB
  unsigned*       link  = (unsigned*)alloc((size_t)NEDGE*4);            // 2 MB
  int*            cmapA = (int*)alloc((size_t)NKEYS*4);                 // 2 MB
  int*            cmapB = (int*)alloc((size_t)NKEYS*4);                 // 2 MB
  unsigned short* aggc  = (unsigned short*)alloc(((size_t)NKEYS+1)*H_*2); // 128 MB
  (void)ws_size; (void)in_sizes; (void)n_in; (void)out_size;

  const int hARow   = (int)(((char*)hA   - ws) >> 8);   // 0
  const int hBRow   = (int)(((char*)hB   - ws) >> 8);
  const int aggcRow = (int)(((char*)aggc - ws) >> 8);
  const unsigned short* vbase = (const unsigned short*)ws;

  // edge chains + virtual-row maps
  hipMemsetAsync(head, 0xFF, (size_t)NKEYS*4, stream);
  hipLaunchKernelGGL(link_k, dim3(NEDGE/256), dim3(256), 0, stream, et, ec, head, link);
  hipLaunchKernelGGL(cmap_k, dim3(NKEYS/256), dim3(256), 0, stream, head, link, medge,
                     cmapA, cmapB, hARow, hBRow, aggcRow);

  // h0 = bf16(embed[class]);  W -> bf16 [r][n][k];  zero slot 0 of aggc
  hipLaunchKernelGGL(prep_k, dim3((B_*N_*32 + 2*R_*H_*H_ + R_*OUT_*H_)/256), dim3(256), 0, stream,
                     cls, emb, W1, W2, W3, hA, W1t, W2t, W3t, aggc);

  const int aggGrid = (NKEYS*4)/256;   // 8192
  const int g128    = (B_*N_)/128;     // 256 blocks x 1024 thr
  const int g32     = (B_*N_)/64;      // 512 blocks x 512 thr

  // layer 1 (h = hA, zero-copy rows via cmapA)
  hipLaunchKernelGGL(agg_k, dim3(aggGrid), dim3(256), 0, stream, hA, head, link, medge, aggc);
  hipLaunchKernelGGL((gemm_k<128>), dim3(g128), dim3(1024), 0, stream,
                     vbase, cmapA, W1t, (const float*)nullptr, hB, (float*)nullptr);
  // layer 2 (h = hB)
  hipLaunchKernelGGL(agg_k, dim3(aggGrid), dim3(256), 0, stream, hB, head, link, medge, aggc);
  hipLaunchKernelGGL((gemm_k<128>), dim3(g128), dim3(1024), 0, stream,
                     vbase, cmapB, W2t, (const float*)nullptr, hA, (float*)nullptr);
  // layer 3 (h = hA, + fused softmax * mask)
  hipLaunchKernelGGL(agg_k, dim3(aggGrid), dim3(256), 0, stream, hA, head, link, medge, aggc);
  hipLaunchKernelGGL((gemm_k<32>), dim3(g32), dim3(512), 0, stream,
                     vbase, cmapA, W3t, mobj, (unsigned short*)nullptr, out);
}